// Round 6
// baseline (1624.164 us; speedup 1.0000x reference)
//
#include <hip/hip_runtime.h>
#include <math.h>

#define DEPTH 17
#define NNODES ((1 << DEPTH) - 1)

typedef _Float16 f16x8 __attribute__((ext_vector_type(8)));
typedef float f32x4 __attribute__((ext_vector_type(4)));

__device__ __forceinline__ float sigmoid_(float v) {
  return 1.0f / (1.0f + __expf(-v));
}
__device__ __forceinline__ float tanh_(float v) {
  float t = __expf(-2.0f * fabsf(v));
  float r = (1.0f - t) / (1.0f + t);
  return v < 0.0f ? -r : r;
}
__device__ __forceinline__ f16x8 pack8(const float4& a, const float4& b) {
  f16x8 r;
  r[0] = (_Float16)a.x; r[1] = (_Float16)a.y;
  r[2] = (_Float16)a.z; r[3] = (_Float16)a.w;
  r[4] = (_Float16)b.x; r[5] = (_Float16)b.y;
  r[6] = (_Float16)b.z; r[7] = (_Float16)b.w;
  return r;
}

// Lane-order-packed weights: for each (nb, w, g, cb) a 16x32 f16 tile stored
// so lane (q*16+l15) holds elems l15*32 + q*8 .. +7 -> one wave B-fragment =
// contiguous 1 KB, coalesced, L2-resident (1.97 MB total).
// Logical col = g*256 + nb*64 + w*16 + l15; cols 0..767 = [W_iou|U_iou],
// 768..1279 = [0|U_f_w] (f-gates), K contiguous.
__global__ __launch_bounds__(256) void build_wb2(
    _Float16* __restrict__ Wb2, const float* __restrict__ W_iou,
    const float* __restrict__ U_iou, const float* __restrict__ U_f_w) {
  int idx = blockIdx.x * 256 + threadIdx.x;  // grid covers 1280*768 exactly
  int within = idx & 511;                    // l15*32 + kk
  int blk = idx >> 9;                        // ((nb*4+w)*5 + g)*24 + cb
  int l15 = within >> 5;
  int kk = within & 31;
  int cb = blk % 24;
  int t = blk / 24;
  int g = t % 5;
  int t2 = t / 5;
  int w = t2 & 3;
  int nb = t2 >> 2;
  int col = g * 256 + nb * 64 + w * 16 + l15;
  int k = cb * 32 + kk;
  float v;
  if (col < 768)
    v = (k < 256) ? W_iou[col * 256 + k] : U_iou[col * 512 + (k - 256)];
  else
    v = (k < 256) ? 0.0f : U_f_w[(col - 768) * 512 + (k - 256)];
  Wb2[idx] = (_Float16)v;
}

// One level: fused GEMM (A[m,K] @ Wb^T) + TreeLSTM node apply.
// Block tile 64 rows x 64 n (x NG groups); 4 waves; wave w owns all 64 rows
// for n = nb*64 + w*16 + l15 -> wave-local epilogue. A: LDS double-buffered,
// reg-staged dist-2 prefetch; B: register ping-pong from lane-packed Wb2
// (L2-resident, never in LDS). Epilogue transposes through LDS: coalesced
// vector loads/stores only at the global level.
template <bool LEAF, bool H16, int MINW, typename CT>
__global__ __launch_bounds__(256, MINW) void level_kernel(
    const float* __restrict__ x, const float* __restrict__ c0in,
    const _Float16* __restrict__ Wb2, const float* __restrict__ b_iou,
    const float* __restrict__ U_f_b, float* __restrict__ out,
    CT* __restrict__ cws, _Float16* __restrict__ hws, int m, int off,
    int coff) {
  constexpr int NG = LEAF ? 3 : 5;    // gate groups of 64 output cols
  constexpr int NCH = LEAF ? 4 : 12;  // K / 64 (even)
  constexpr int NBU = NG * 2;         // B f16x8 fragments per chunk
  __shared__ __align__(16) char smem[32768];
  f16x8* sA = (f16x8*)smem;           // main loop: [2][512] = 16 KB

  const int tid = threadIdx.x;
  const int w = tid >> 6;
  const int lane = tid & 63;
  const int l15 = lane & 15;
  const int q = lane >> 4;

  // XCD-grouped mapping: all 4 nb-splits of a row-group share bid%8 (same
  // XCD L2) within one 32-block dispatch window. Requires gridDim%32==0.
  int bx = blockIdx.x, r, nb;
  if ((gridDim.x & 31) == 0) {
    nb = (bx >> 3) & 3;
    r = ((bx >> 5) << 3) + (bx & 7);
  } else {
    r = bx >> 2;
    nb = bx & 3;
  }
  const int pbase = r << 6;

  const int arow = tid >> 3;  // staging row for unit 0 (unit j: +32)
  const int akc = tid & 7;    // 16B unit within 64-k row

  // ---- issue global A loads for chunk c into a register set (no waits)
  auto LOADA = [&](float4 (&ax)[2][2], f16x8 (&ah)[2], int c) {
    const int k0 = (c << 6) + (akc << 3);
#pragma unroll
    for (int j = 0; j < 2; ++j) {
      const int row = arow + j * 32;
      const int p = pbase + row;
      const bool xpart = LEAF || c < 4;
      if (p < m) {
        if (xpart) {
          const float* src = x + (size_t)(off + p) * 256 + k0;
          ax[j][0] = *(const float4*)src;
          ax[j][1] = *(const float4*)(src + 4);
        } else if (H16) {
          ah[j] = *(const f16x8*)(hws + (size_t)(coff + 2 * p) * 256 +
                                  (k0 - 256));
        } else {
          const float* src = out + (size_t)(coff + 2 * p) * 256 + (k0 - 256);
          ax[j][0] = *(const float4*)src;
          ax[j][1] = *(const float4*)(src + 4);
        }
      } else {
        ax[j][0] = float4{0.f, 0.f, 0.f, 0.f};
        ax[j][1] = float4{0.f, 0.f, 0.f, 0.f};
        f16x8 z = {};
        ah[j] = z;
      }
    }
  };

  // ---- convert + ds_write a staged set into swizzled slots of buf c&1
  auto WRITEA = [&](float4 (&ax)[2][2], f16x8 (&ah)[2], int c) {
#pragma unroll
    for (int j = 0; j < 2; ++j) {
      const int row = arow + j * 32;
      f16x8 v;
      if (H16 && !LEAF && c >= 4) {
        v = ah[j];
      } else {
        v = pack8(ax[j][0], ax[j][1]);
      }
      sA[((c & 1) << 9) | (row << 3) | (akc ^ (row & 7))] = v;
    }
  };

  // per-wave packed B base; (g, cb=c*2+ks) tile at + (g*24 + cb)*512
  const _Float16* bb =
      Wb2 + (size_t)(nb * 4 + w) * (5 * 24 * 512) + l15 * 32 + q * 8;
  auto LOADB = [&](f16x8 (&bv)[NBU], int c) {
#pragma unroll
    for (int j = 0; j < NBU; ++j)
      bv[j] = *(const f16x8*)(bb + (((j >> 1) * 24 + c * 2 + (j & 1)) << 9));
  };

  f32x4 acc[NG][4] = {};

  auto COMPUTE = [&](int buf, f16x8 (&bv)[NBU]) {
    __builtin_amdgcn_s_setprio(1);
#pragma unroll
    for (int ks = 0; ks < 2; ++ks) {
      f16x8 af[4];
#pragma unroll
      for (int rf = 0; rf < 4; ++rf) {
        const int row = rf * 16 + l15;
        af[rf] = sA[(buf << 9) | (row << 3) | ((ks * 4 + q) ^ (row & 7))];
      }
#pragma unroll
      for (int g = 0; g < NG; ++g) {
        const f16x8 bf = bv[g * 2 + ks];
#pragma unroll
        for (int rf = 0; rf < 4; ++rf)
          acc[g][rf] = __builtin_amdgcn_mfma_f32_16x16x32_f16(
              af[rf], bf, acc[g][rf], 0, 0, 0);
      }
    }
    __builtin_amdgcn_s_setprio(0);
  };

  float4 axA[2][2], axB[2][2];
  f16x8 ahA[2], ahB[2];
  f16x8 bvA[NBU], bvB[NBU];

  LOADA(axA, ahA, 0);
  LOADB(bvA, 0);
  WRITEA(axA, ahA, 0);
  LOADA(axB, ahB, 1);
  LOADB(bvB, 1);
  __syncthreads();

  for (int c = 0; c < NCH; c += 2) {
    if (c + 2 < NCH) LOADA(axA, ahA, c + 2);
    COMPUTE(0, bvA);                          // chunk c
    WRITEA(axB, ahB, c + 1);
    if (c + 2 < NCH) LOADB(bvA, c + 2);
    __syncthreads();
    if (c + 3 < NCH) LOADA(axB, ahB, c + 3);
    COMPUTE(1, bvB);                          // chunk c+1
    if (c + 2 < NCH) {
      WRITEA(axA, ahA, c + 2);
      if (c + 3 < NCH) LOADB(bvB, c + 3);
      __syncthreads();
    }
  }
  __syncthreads();  // main loop done; smem is free for the epilogue

  // ================= epilogue (all global I/O coalesced via LDS) ==========
  const int erow = tid >> 2;   // 0..63
  const int eseg = tid & 3;    // 64B segment within a 64-f32 row
  float* cf = (float*)smem;

  // ---- E1: stage c-input tile into f32 LDS
  if (LEAF) {
    // c0 tile 64x64 f32 (16 KB), no swizzle (2-way on read pattern is free)
    const int p = pbase + erow;
    float4 v[4] = {float4{0,0,0,0}, float4{0,0,0,0}, float4{0,0,0,0},
                   float4{0,0,0,0}};
    if (p < m) {
      const float* src = c0in + (size_t)(off + p) * 256 + nb * 64 + eseg * 16;
#pragma unroll
      for (int j = 0; j < 4; ++j) v[j] = *(const float4*)(src + j * 4);
    }
#pragma unroll
    for (int j = 0; j < 4; ++j)
      *(float4*)&cf[erow * 64 + eseg * 16 + j * 4] = v[j];
  } else {
    // c-children tile 128x64 f32 (32 KB), 64B-unit XOR swizzle ^((row&3)<<6)
#pragma unroll
    for (int pass = 0; pass < 2; ++pass) {
      const int row = pass * 64 + erow;  // child-local row 0..127
      float4 v[4] = {float4{0,0,0,0}, float4{0,0,0,0}, float4{0,0,0,0},
                     float4{0,0,0,0}};
      if (row < 2 * (m - pbase)) {
        const CT* src = cws + (size_t)(coff + 2 * pbase + row) * 256 +
                        nb * 64 + eseg * 16;
        if constexpr (sizeof(CT) == 2) {
          f16x8 t0 = *(const f16x8*)src;
          f16x8 t1 = *(const f16x8*)(src + 8);
          v[0] = float4{(float)t0[0], (float)t0[1], (float)t0[2], (float)t0[3]};
          v[1] = float4{(float)t0[4], (float)t0[5], (float)t0[6], (float)t0[7]};
          v[2] = float4{(float)t1[0], (float)t1[1], (float)t1[2], (float)t1[3]};
          v[3] = float4{(float)t1[4], (float)t1[5], (float)t1[6], (float)t1[7]};
        } else {
#pragma unroll
          for (int j = 0; j < 4; ++j)
            v[j] = *(const float4*)((const float*)src + j * 4);
        }
      }
#pragma unroll
      for (int j = 0; j < 4; ++j) {
        const int byte = row * 256 + ((eseg * 64 + j * 16) ^ ((row & 3) << 6));
        *(float4*)(smem + byte) = v[j];
      }
    }
  }
  __syncthreads();

  // ---- E2: gate math (inputs scatter-read from LDS; once per block)
  const int n = nb * 64 + w * 16 + l15;  // n in [0,256)
  const float bi = b_iou[n];
  const float bo = b_iou[256 + n];
  const float bu = b_iou[512 + n];
  float bf0 = 0.f, bf1 = 0.f;
  if (!LEAF) { bf0 = U_f_b[n]; bf1 = U_f_b[256 + n]; }
  float hv[16], cv[16];
#pragma unroll
  for (int rf = 0; rf < 4; ++rf) {
#pragma unroll
    for (int rr = 0; rr < 4; ++rr) {
      const int idx = rf * 4 + rr;
      const int prow = rf * 16 + (q << 2) + rr;  // row within 64-row tile
      const float iv = sigmoid_(acc[0][rf][rr] + bi);
      const float ov = sigmoid_(acc[1][rf][rr] + bo);
      const float uv = tanh_(acc[2][rf][rr] + bu);
      float cred;
      if (LEAF) {
        cred = cf[prow * 64 + (w << 4) + l15];
      } else {
        const int r0 = 2 * prow, r1 = 2 * prow + 1;
        const int colb = ((w << 4) + l15) * 4;
        const float c0v =
            *(const float*)(smem + r0 * 256 + (colb ^ ((r0 & 3) << 6)));
        const float c1v =
            *(const float*)(smem + r1 * 256 + (colb ^ ((r1 & 3) << 6)));
        const float f0 = sigmoid_(acc[3][rf][rr] + bf0);
        const float f1 = sigmoid_(acc[4][rf][rr] + bf1);
        cred = f0 * c0v + f1 * c1v;
      }
      const float cc = iv * uv + cred;
      hv[idx] = ov * tanh_(cc);
      cv[idx] = cc;
    }
  }
  __syncthreads();

  // ---- E3: scatter h,c f32 into LDS tiles (h at 0, c at 16 KB)
  float* hf = (float*)smem;
  float* cf2 = (float*)(smem + 16384);
#pragma unroll
  for (int rf = 0; rf < 4; ++rf) {
#pragma unroll
    for (int rr = 0; rr < 4; ++rr) {
      const int idx = rf * 4 + rr;
      const int prow = rf * 16 + (q << 2) + rr;
      hf[prow * 64 + (w << 4) + l15] = hv[idx];
      cf2[prow * 64 + (w << 4) + l15] = cv[idx];
    }
  }
  __syncthreads();

  // ---- E4: coalesced vector stores
  {
    const int p = pbase + erow;
    if (p < m) {
      float4 h4[4], c4[4];
#pragma unroll
      for (int j = 0; j < 4; ++j) {
        h4[j] = *(const float4*)&hf[erow * 64 + eseg * 16 + j * 4];
        c4[j] = *(const float4*)&cf2[erow * 64 + eseg * 16 + j * 4];
      }
      const size_t ob = (size_t)(off + p) * 256 + nb * 64 + eseg * 16;
      float* dst = out + ob;
#pragma unroll
      for (int j = 0; j < 4; ++j) *(float4*)(dst + j * 4) = h4[j];
      if (H16) {
        *(f16x8*)(hws + ob) = pack8(h4[0], h4[1]);
        *(f16x8*)(hws + ob + 8) = pack8(h4[2], h4[3]);
      }
      if constexpr (sizeof(CT) == 2) {
        *(f16x8*)((_Float16*)cws + ob) = pack8(c4[0], c4[1]);
        *(f16x8*)((_Float16*)cws + ob + 8) = pack8(c4[2], c4[3]);
      } else {
        float* cdst = (float*)cws + ob;
#pragma unroll
        for (int j = 0; j < 4; ++j) *(float4*)(cdst + j * 4) = c4[j];
      }
    }
  }
}

template <bool H16, typename CT>
static void run_levels(const float* x, const float* c0, const _Float16* Wb2,
                       const float* b_iou, const float* U_f_b, float* out,
                       CT* cws, _Float16* hws, hipStream_t stream) {
  // leaves: level 16, m = 65536, off = 65535
  level_kernel<true, H16, 4, CT><<<dim3(4096), 256, 0, stream>>>(
      x, c0, Wb2, b_iou, U_f_b, out, cws, hws, 65536, 65535, 0);
  for (int k = DEPTH - 2; k >= 0; --k) {
    const int m = 1 << k;
    const int R = (m + 63) / 64;
    level_kernel<false, H16, 3, CT><<<dim3(R * 4), 256, 0, stream>>>(
        x, c0, Wb2, b_iou, U_f_b, out, cws, hws, m, m - 1, 2 * m - 1);
  }
}

extern "C" void kernel_launch(void* const* d_in, const int* in_sizes, int n_in,
                              void* d_out, int out_size, void* d_ws, size_t ws_size,
                              hipStream_t stream) {
  const float* x     = (const float*)d_in[0];
  // d_in[1] = h0 (unused by the reference's math)
  const float* c0    = (const float*)d_in[2];
  const float* W_iou = (const float*)d_in[3];
  const float* U_iou = (const float*)d_in[4];
  const float* b_iou = (const float*)d_in[5];
  const float* U_f_w = (const float*)d_in[6];
  const float* U_f_b = (const float*)d_in[7];
  float* out = (float*)d_out;

  char* ws = (char*)d_ws;
  const size_t wbBytes = (size_t)1280 * 768 * 2;  // 1.97 MB, 16B-aligned
  _Float16* Wb2 = (_Float16*)ws;
  build_wb2<<<3840, 256, 0, stream>>>(Wb2, W_iou, U_iou, U_f_w);

  const size_t cElems = (size_t)NNODES * 256;
  char* p1 = ws + wbBytes;
  if (ws_size >= wbBytes + cElems * 2 + cElems * 2) {
    // c in f16 (halved traffic) + h mirrored in f16 for the parent GEMM
    run_levels<true, _Float16>(x, c0, Wb2, b_iou, U_f_b, out, (_Float16*)p1,
                               (_Float16*)(p1 + cElems * 2), stream);
  } else if (ws_size >= wbBytes + cElems * 4) {
    run_levels<false, float>(x, c0, Wb2, b_iou, U_f_b, out, (float*)p1,
                             nullptr, stream);
  } else {
    run_levels<false, _Float16>(x, c0, Wb2, b_iou, U_f_b, out, (_Float16*)p1,
                                nullptr, stream);
  }
}

// Round 7
// 554.912 us; speedup vs baseline: 2.9269x; 2.9269x over previous
//
#include <hip/hip_runtime.h>
#include <math.h>

#define DEPTH 17
#define NNODES ((1 << DEPTH) - 1)

typedef _Float16 f16x8 __attribute__((ext_vector_type(8)));
typedef float f32x4 __attribute__((ext_vector_type(4)));

__device__ __forceinline__ float sigmoid_(float v) {
  return 1.0f / (1.0f + __expf(-v));
}
__device__ __forceinline__ float tanh_(float v) {
  float t = __expf(-2.0f * fabsf(v));
  float r = (1.0f - t) / (1.0f + t);
  return v < 0.0f ? -r : r;
}
__device__ __forceinline__ f16x8 pack8(const float4& a, const float4& b) {
  f16x8 r;
  r[0] = (_Float16)a.x; r[1] = (_Float16)a.y;
  r[2] = (_Float16)a.z; r[3] = (_Float16)a.w;
  r[4] = (_Float16)b.x; r[5] = (_Float16)b.y;
  r[6] = (_Float16)b.z; r[7] = (_Float16)b.w;
  return r;
}

// Lane-order-packed weights: for each (nb, w, g, cb) a 16x32 f16 tile stored
// so lane (q*16+l15) holds elems l15*32 + q*8 .. +7 -> one wave B-fragment =
// contiguous 1 KB, coalesced, L2-resident (1.97 MB total).
// Logical col = g*256 + nb*64 + w*16 + l15; cols 0..767 = [W_iou|U_iou],
// 768..1279 = [0|U_f_w] (f-gates), K contiguous.
__global__ __launch_bounds__(256) void build_wb2(
    _Float16* __restrict__ Wb2, const float* __restrict__ W_iou,
    const float* __restrict__ U_iou, const float* __restrict__ U_f_w) {
  int idx = blockIdx.x * 256 + threadIdx.x;  // grid covers 1280*768 exactly
  int within = idx & 511;                    // l15*32 + kk
  int blk = idx >> 9;                        // ((nb*4+w)*5 + g)*24 + cb
  int l15 = within >> 5;
  int kk = within & 31;
  int cb = blk % 24;
  int t = blk / 24;
  int g = t % 5;
  int t2 = t / 5;
  int w = t2 & 3;
  int nb = t2 >> 2;
  int col = g * 256 + nb * 64 + w * 16 + l15;
  int k = cb * 32 + kk;
  float v;
  if (col < 768)
    v = (k < 256) ? W_iou[col * 256 + k] : U_iou[col * 512 + (k - 256)];
  else
    v = (k < 256) ? 0.0f : U_f_w[(col - 768) * 512 + (k - 256)];
  Wb2[idx] = (_Float16)v;
}

// One level: fused GEMM (A[m,K] @ Wb^T) + TreeLSTM node apply.
// Block tile 64 rows x 64 n (x NG groups); 4 waves; wave w owns all 64 rows
// for n = nb*64 + w*16 + l15 -> wave-local epilogue. A: LDS double-buffered,
// reg-staged dist-2 prefetch; B: register ping-pong from lane-packed Wb2
// (L2-resident, never in LDS). Epilogue transposes through LDS so all global
// I/O is vector+coalesced. launch_bounds min-waves MUST stay 2: the pipeline
// holds ~220 VGPRs; 3 waves/EU budget (168) spills to scratch (R6: 1 GB/dsp).
template <bool LEAF, bool H16, typename CT>
__global__ __launch_bounds__(256, 2) void level_kernel(
    const float* __restrict__ x, const float* __restrict__ c0in,
    const _Float16* __restrict__ Wb2, const float* __restrict__ b_iou,
    const float* __restrict__ U_f_b, float* __restrict__ out,
    CT* __restrict__ cws, _Float16* __restrict__ hws, int m, int off,
    int coff) {
  constexpr int NG = LEAF ? 3 : 5;    // gate groups of 64 output cols
  constexpr int NCH = LEAF ? 4 : 12;  // K / 64 (even)
  constexpr int NBU = NG * 2;         // B f16x8 fragments per chunk
  __shared__ __align__(16) char smem[32768];
  f16x8* sA = (f16x8*)smem;           // main loop: [2][512] = 16 KB

  const int tid = threadIdx.x;
  const int w = tid >> 6;
  const int lane = tid & 63;
  const int l15 = lane & 15;
  const int q = lane >> 4;

  // XCD-grouped mapping: all 4 nb-splits of a row-group share bid%8 (same
  // XCD L2) within one 32-block dispatch window. Requires gridDim%32==0.
  int bx = blockIdx.x, r, nb;
  if ((gridDim.x & 31) == 0) {
    nb = (bx >> 3) & 3;
    r = ((bx >> 5) << 3) + (bx & 7);
  } else {
    r = bx >> 2;
    nb = bx & 3;
  }
  const int pbase = r << 6;

  const int arow = tid >> 3;  // staging row for unit 0 (unit j: +32)
  const int akc = tid & 7;    // 16B unit within 64-k row

  // ---- issue global A loads for chunk c into a register set (no waits)
  auto LOADA = [&](float4 (&ax)[2][2], f16x8 (&ah)[2], int c) {
    const int k0 = (c << 6) + (akc << 3);
#pragma unroll
    for (int j = 0; j < 2; ++j) {
      const int row = arow + j * 32;
      const int p = pbase + row;
      const bool xpart = LEAF || c < 4;
      if (p < m) {
        if (xpart) {
          const float* src = x + (size_t)(off + p) * 256 + k0;
          ax[j][0] = *(const float4*)src;
          ax[j][1] = *(const float4*)(src + 4);
        } else if (H16) {
          ah[j] = *(const f16x8*)(hws + (size_t)(coff + 2 * p) * 256 +
                                  (k0 - 256));
        } else {
          const float* src = out + (size_t)(coff + 2 * p) * 256 + (k0 - 256);
          ax[j][0] = *(const float4*)src;
          ax[j][1] = *(const float4*)(src + 4);
        }
      } else {
        ax[j][0] = float4{0.f, 0.f, 0.f, 0.f};
        ax[j][1] = float4{0.f, 0.f, 0.f, 0.f};
        f16x8 z = {};
        ah[j] = z;
      }
    }
  };

  // ---- convert + ds_write a staged set into swizzled slots of buf c&1
  auto WRITEA = [&](float4 (&ax)[2][2], f16x8 (&ah)[2], int c) {
#pragma unroll
    for (int j = 0; j < 2; ++j) {
      const int row = arow + j * 32;
      f16x8 v;
      if (H16 && !LEAF && c >= 4) {
        v = ah[j];
      } else {
        v = pack8(ax[j][0], ax[j][1]);
      }
      sA[((c & 1) << 9) | (row << 3) | (akc ^ (row & 7))] = v;
    }
  };

  // per-wave packed B base; (g, cb=c*2+ks) tile at + (g*24 + cb)*512
  const _Float16* bb =
      Wb2 + (size_t)(nb * 4 + w) * (5 * 24 * 512) + l15 * 32 + q * 8;
  auto LOADB = [&](f16x8 (&bv)[NBU], int c) {
#pragma unroll
    for (int j = 0; j < NBU; ++j)
      bv[j] = *(const f16x8*)(bb + (((j >> 1) * 24 + c * 2 + (j & 1)) << 9));
  };

  f32x4 acc[NG][4] = {};

  auto COMPUTE = [&](int buf, f16x8 (&bv)[NBU]) {
    __builtin_amdgcn_s_setprio(1);
#pragma unroll
    for (int ks = 0; ks < 2; ++ks) {
      f16x8 af[4];
#pragma unroll
      for (int rf = 0; rf < 4; ++rf) {
        const int row = rf * 16 + l15;
        af[rf] = sA[(buf << 9) | (row << 3) | ((ks * 4 + q) ^ (row & 7))];
      }
#pragma unroll
      for (int g = 0; g < NG; ++g) {
        const f16x8 bf = bv[g * 2 + ks];
#pragma unroll
        for (int rf = 0; rf < 4; ++rf)
          acc[g][rf] = __builtin_amdgcn_mfma_f32_16x16x32_f16(
              af[rf], bf, acc[g][rf], 0, 0, 0);
      }
    }
    __builtin_amdgcn_s_setprio(0);
  };

  float4 axA[2][2], axB[2][2];
  f16x8 ahA[2], ahB[2];
  f16x8 bvA[NBU], bvB[NBU];

  LOADA(axA, ahA, 0);
  LOADB(bvA, 0);
  WRITEA(axA, ahA, 0);
  LOADA(axB, ahB, 1);
  LOADB(bvB, 1);
  __syncthreads();

  for (int c = 0; c < NCH; c += 2) {
    if (c + 2 < NCH) LOADA(axA, ahA, c + 2);
    COMPUTE(0, bvA);                          // chunk c
    WRITEA(axB, ahB, c + 1);
    if (c + 2 < NCH) LOADB(bvA, c + 2);
    __syncthreads();
    if (c + 3 < NCH) LOADA(axB, ahB, c + 3);
    COMPUTE(1, bvB);                          // chunk c+1
    if (c + 2 < NCH) {
      WRITEA(axA, ahA, c + 2);
      if (c + 3 < NCH) LOADB(bvB, c + 3);
      __syncthreads();
    }
  }
  __syncthreads();  // main loop done; smem is free for the epilogue

  // ================= epilogue (all global I/O coalesced via LDS) ==========
  // Swizzles: 64-col f32 tiles flip the 16-float window with the row's
  // q-parity bit -> scatter phases are 2-way (free) instead of 4-way.
  const int erow = tid >> 2;   // 0..63
  const int eseg = tid & 3;    // 16-float window within a 64-f32 row
  float* cf = (float*)smem;

  // ---- E1: stage c-input tile into f32 LDS
  if (LEAF) {
    // c0 tile 64x64 f32 (16 KB); window ^= row's bit2 (q parity on read)
    const int p = pbase + erow;
    float4 v[4] = {float4{0,0,0,0}, float4{0,0,0,0}, float4{0,0,0,0},
                   float4{0,0,0,0}};
    if (p < m) {
      const float* src = c0in + (size_t)(off + p) * 256 + nb * 64 + eseg * 16;
#pragma unroll
      for (int j = 0; j < 4; ++j) v[j] = *(const float4*)(src + j * 4);
    }
    const int we = (eseg ^ ((erow >> 2) & 1)) * 16;
#pragma unroll
    for (int j = 0; j < 4; ++j)
      *(float4*)&cf[erow * 64 + we + j * 4] = v[j];
  } else {
    // c-children tile 128x64 f32 (32 KB); byte bit6 ^= (row>>3)&1 (=q parity
    // for both children of the rows wave-q owns)
#pragma unroll
    for (int pass = 0; pass < 2; ++pass) {
      const int row = pass * 64 + erow;  // child-local row 0..127
      float4 v[4] = {float4{0,0,0,0}, float4{0,0,0,0}, float4{0,0,0,0},
                     float4{0,0,0,0}};
      if (row < 2 * (m - pbase)) {
        const CT* src = cws + (size_t)(coff + 2 * pbase + row) * 256 +
                        nb * 64 + eseg * 16;
        if constexpr (sizeof(CT) == 2) {
          f16x8 t0 = *(const f16x8*)src;
          f16x8 t1 = *(const f16x8*)(src + 8);
          v[0] = float4{(float)t0[0], (float)t0[1], (float)t0[2], (float)t0[3]};
          v[1] = float4{(float)t0[4], (float)t0[5], (float)t0[6], (float)t0[7]};
          v[2] = float4{(float)t1[0], (float)t1[1], (float)t1[2], (float)t1[3]};
          v[3] = float4{(float)t1[4], (float)t1[5], (float)t1[6], (float)t1[7]};
        } else {
#pragma unroll
          for (int j = 0; j < 4; ++j)
            v[j] = *(const float4*)((const float*)src + j * 4);
        }
      }
      const int sw6 = ((row >> 3) & 1) << 6;
#pragma unroll
      for (int j = 0; j < 4; ++j) {
        const int byte = row * 256 + ((eseg * 64 + j * 16) ^ sw6);
        *(float4*)(smem + byte) = v[j];
      }
    }
  }
  __syncthreads();

  // ---- E2: gate math (inputs scatter-read from LDS; once per block)
  const int n = nb * 64 + w * 16 + l15;  // n in [0,256)
  const float bi = b_iou[n];
  const float bo = b_iou[256 + n];
  const float bu = b_iou[512 + n];
  float bf0 = 0.f, bf1 = 0.f;
  if (!LEAF) { bf0 = U_f_b[n]; bf1 = U_f_b[256 + n]; }
  float hv[16], cv[16];
#pragma unroll
  for (int rf = 0; rf < 4; ++rf) {
#pragma unroll
    for (int rr = 0; rr < 4; ++rr) {
      const int idx = rf * 4 + rr;
      const int prow = rf * 16 + (q << 2) + rr;  // row within 64-row tile
      const float iv = sigmoid_(acc[0][rf][rr] + bi);
      const float ov = sigmoid_(acc[1][rf][rr] + bo);
      const float uv = tanh_(acc[2][rf][rr] + bu);
      float cred;
      if (LEAF) {
        cred = cf[prow * 64 + ((w ^ ((prow >> 2) & 1)) << 4) + l15];
      } else {
        const int r0 = 2 * prow, r1 = 2 * prow + 1;
        const int colb = ((w << 4) + l15) * 4;
        const float c0v = *(const float*)(
            smem + r0 * 256 + (colb ^ (((r0 >> 3) & 1) << 6)));
        const float c1v = *(const float*)(
            smem + r1 * 256 + (colb ^ (((r1 >> 3) & 1) << 6)));
        const float f0 = sigmoid_(acc[3][rf][rr] + bf0);
        const float f1 = sigmoid_(acc[4][rf][rr] + bf1);
        cred = f0 * c0v + f1 * c1v;
      }
      const float cc = iv * uv + cred;
      hv[idx] = ov * tanh_(cc);
      cv[idx] = cc;
    }
  }
  __syncthreads();

  // ---- E3: scatter h,c f32 into LDS tiles (h at 0, c at 16 KB), swizzled
  float* hf = (float*)smem;
  float* cf2 = (float*)(smem + 16384);
#pragma unroll
  for (int rf = 0; rf < 4; ++rf) {
#pragma unroll
    for (int rr = 0; rr < 4; ++rr) {
      const int idx = rf * 4 + rr;
      const int prow = rf * 16 + (q << 2) + rr;
      const int col = ((w ^ ((prow >> 2) & 1)) << 4) + l15;
      hf[prow * 64 + col] = hv[idx];
      cf2[prow * 64 + col] = cv[idx];
    }
  }
  __syncthreads();

  // ---- E4: coalesced vector stores
  {
    const int p = pbase + erow;
    if (p < m) {
      const int we = (eseg ^ ((erow >> 2) & 1)) * 16;
      float4 h4[4], c4[4];
#pragma unroll
      for (int j = 0; j < 4; ++j) {
        h4[j] = *(const float4*)&hf[erow * 64 + we + j * 4];
        c4[j] = *(const float4*)&cf2[erow * 64 + we + j * 4];
      }
      const size_t ob = (size_t)(off + p) * 256 + nb * 64 + eseg * 16;
      float* dst = out + ob;
#pragma unroll
      for (int j = 0; j < 4; ++j) *(float4*)(dst + j * 4) = h4[j];
      if (H16) {
        *(f16x8*)(hws + ob) = pack8(h4[0], h4[1]);
        *(f16x8*)(hws + ob + 8) = pack8(h4[2], h4[3]);
      }
      if constexpr (sizeof(CT) == 2) {
        *(f16x8*)((_Float16*)cws + ob) = pack8(c4[0], c4[1]);
        *(f16x8*)((_Float16*)cws + ob + 8) = pack8(c4[2], c4[3]);
      } else {
        float* cdst = (float*)cws + ob;
#pragma unroll
        for (int j = 0; j < 4; ++j) *(float4*)(cdst + j * 4) = c4[j];
      }
    }
  }
}

template <bool H16, typename CT>
static void run_levels(const float* x, const float* c0, const _Float16* Wb2,
                       const float* b_iou, const float* U_f_b, float* out,
                       CT* cws, _Float16* hws, hipStream_t stream) {
  // leaves: level 16, m = 65536, off = 65535
  level_kernel<true, H16, CT><<<dim3(4096), 256, 0, stream>>>(
      x, c0, Wb2, b_iou, U_f_b, out, cws, hws, 65536, 65535, 0);
  for (int k = DEPTH - 2; k >= 0; --k) {
    const int m = 1 << k;
    const int R = (m + 63) / 64;
    level_kernel<false, H16, CT><<<dim3(R * 4), 256, 0, stream>>>(
        x, c0, Wb2, b_iou, U_f_b, out, cws, hws, m, m - 1, 2 * m - 1);
  }
}

extern "C" void kernel_launch(void* const* d_in, const int* in_sizes, int n_in,
                              void* d_out, int out_size, void* d_ws, size_t ws_size,
                              hipStream_t stream) {
  const float* x     = (const float*)d_in[0];
  // d_in[1] = h0 (unused by the reference's math)
  const float* c0    = (const float*)d_in[2];
  const float* W_iou = (const float*)d_in[3];
  const float* U_iou = (const float*)d_in[4];
  const float* b_iou = (const float*)d_in[5];
  const float* U_f_w = (const float*)d_in[6];
  const float* U_f_b = (const float*)d_in[7];
  float* out = (float*)d_out;

  char* ws = (char*)d_ws;
  const size_t wbBytes = (size_t)1280 * 768 * 2;  // 1.97 MB, 16B-aligned
  _Float16* Wb2 = (_Float16*)ws;
  build_wb2<<<3840, 256, 0, stream>>>(Wb2, W_iou, U_iou, U_f_w);

  const size_t cElems = (size_t)NNODES * 256;
  char* p1 = ws + wbBytes;
  if (ws_size >= wbBytes + cElems * 2 + cElems * 2) {
    // c in f16 (halved traffic) + h mirrored in f16 for the parent GEMM
    run_levels<true, _Float16>(x, c0, Wb2, b_iou, U_f_b, out, (_Float16*)p1,
                               (_Float16*)(p1 + cElems * 2), stream);
  } else if (ws_size >= wbBytes + cElems * 4) {
    run_levels<false, float>(x, c0, Wb2, b_iou, U_f_b, out, (float*)p1,
                             nullptr, stream);
  } else {
    run_levels<false, _Float16>(x, c0, Wb2, b_iou, U_f_b, out, (_Float16*)p1,
                                nullptr, stream);
  }
}